// Round 3
// baseline (157.892 us; speedup 1.0000x reference)
//
#include <hip/hip_runtime.h>
#include <hip/hip_bf16.h>

#define IN_SZ   256
#define OUT_SZ  256
#define NNZ_C   2048
#define NB      16      // nodes per block (fallback kernel)
#define BMG     64      // GEMM rows per block

typedef __attribute__((ext_vector_type(8))) short bf16x8;
typedef __attribute__((ext_vector_type(4))) float f32x4;

static __device__ __forceinline__ short f2bf(float f) {
    __hip_bfloat16 h = __float2bfloat16(f);
    return (short)__builtin_bit_cast(unsigned short, h);
}

// ---------------- single builder kernel ----------------
// One block per output column j. Accumulate row j of W^T (=W[j][m]) into LDS
// (f32 atomics, duplicate (j,m) handled), convert to bf16, and scatter into
// the MFMA B-fragment layout the GEMM consumes directly:
//   chunk c = (((wn*4+n)*4+kt)*2+kf)*64 + lane holds 8 consecutive k (bf16)
//   where j = wn*64 + n*16 + (lane&15), k = kt*64 + kf*32 + (lane>>4)*8 + e.

__global__ void build_w(const float* __restrict__ scale,
                        const int*   __restrict__ M_in,
                        const int*   __restrict__ M,
                        unsigned short* __restrict__ wb)
{
    __shared__ float row[IN_SZ];
    const int j = blockIdx.x;
    const int t = threadIdx.x;          // 64 threads

#pragma unroll
    for (int i = t; i < IN_SZ; i += 64) row[i] = 0.f;
    __syncthreads();

#pragma unroll
    for (int k = t; k < NNZ_C; k += 64)
        if (M[k] == j) atomicAdd(&row[M_in[k]], scale[k]);
    __syncthreads();

    const int wn = j >> 6, n = (j >> 4) & 3, l15 = j & 15;
#pragma unroll
    for (int kk = t; kk < IN_SZ; kk += 64) {
        int kt = kk >> 6, kf = (kk >> 5) & 1, lhi = (kk >> 3) & 3, e = kk & 7;
        int lane = lhi * 16 + l15;
        int c = (((wn * 4 + n) * 4 + kt) * 2 + kf) * 64 + lane;
        wb[c * 8 + e] = (unsigned short)f2bf(row[kk]);
    }
}

// ---------------- GEMM: no LDS, no barriers ----------------
// 1024 blocks x 256 thr (4 waves). Block owns 64 rows; wave wn owns 64 cols.
// A fragments loaded straight from global f32 (16 fully-consumed cachelines
// per instruction; 4x wave duplication served by L1). B fragments from the
// pre-arranged ws buffer (perfectly coalesced, L1/L2-resident).

__global__ __launch_bounds__(256, 3)
void gemm_direct(const float* __restrict__ input,
                 const bf16x8* __restrict__ wfrag,
                 float* __restrict__ out)
{
    const int tid  = threadIdx.x;
    const int lane = tid & 63;
    const int wn   = tid >> 6;
    const int l15  = lane & 15, lhi = lane >> 4;
    const long row0 = (long)blockIdx.x * BMG;

    f32x4 acc[4][4];
#pragma unroll
    for (int m = 0; m < 4; ++m)
#pragma unroll
        for (int n = 0; n < 4; ++n)
            acc[m][n] = (f32x4){0.f, 0.f, 0.f, 0.f};

#pragma unroll
    for (int kt = 0; kt < 4; ++kt) {
#pragma unroll
        for (int kf = 0; kf < 2; ++kf) {
            bf16x8 afr[4], bfr[4];
#pragma unroll
            for (int m = 0; m < 4; ++m) {
                const float4* p = (const float4*)(input
                    + (row0 + m * 16 + l15) * IN_SZ + kt * 64 + kf * 32 + lhi * 8);
                float4 x = p[0], y = p[1];
                bf16x8 u;
                u[0] = f2bf(x.x); u[1] = f2bf(x.y); u[2] = f2bf(x.z); u[3] = f2bf(x.w);
                u[4] = f2bf(y.x); u[5] = f2bf(y.y); u[6] = f2bf(y.z); u[7] = f2bf(y.w);
                afr[m] = u;
            }
#pragma unroll
            for (int n = 0; n < 4; ++n)
                bfr[n] = wfrag[(((wn * 4 + n) * 4 + kt) * 2 + kf) * 64 + lane];
#pragma unroll
            for (int m = 0; m < 4; ++m)
#pragma unroll
                for (int n = 0; n < 4; ++n)
                    acc[m][n] = __builtin_amdgcn_mfma_f32_16x16x32_bf16(
                        afr[m], bfr[n], acc[m][n], 0, 0, 0);
        }
    }

    // C/D layout: col = lane&15, row = (lane>>4)*4 + r  (verified rounds 1-2)
#pragma unroll
    for (int m = 0; m < 4; ++m) {
        long r0 = row0 + m * 16 + lhi * 4;
#pragma unroll
        for (int n = 0; n < 4; ++n) {
            int col = wn * 64 + n * 16 + l15;
#pragma unroll
            for (int r = 0; r < 4; ++r)
                out[(r0 + r) * OUT_SZ + col] = acc[m][n][r];
        }
    }
}

// ---------------- fallback: round-1 sparse kernel ----------------

__global__ __launch_bounds__(256, 4)
void sparse_tp_kernel(const float* __restrict__ input,
                      const float* __restrict__ scale,
                      const int*   __restrict__ M_in,
                      const int*   __restrict__ M,
                      float*       __restrict__ out,
                      int N)
{
    __shared__ float s_in[NB * IN_SZ];
    __shared__ float s_scale[NNZ_C];
    __shared__ int   s_min[NNZ_C];
    __shared__ int   s_seg[OUT_SZ + 1];

    const int tid  = threadIdx.x;
    const int base = blockIdx.x * NB;

    {
        const float4* sc4  = reinterpret_cast<const float4*>(scale);
        const int4*   mi4  = reinterpret_cast<const int4*>(M_in);
        float4*       ssc4 = reinterpret_cast<float4*>(s_scale);
        int4*         smi4 = reinterpret_cast<int4*>(s_min);
        for (int v = tid; v < NNZ_C / 4; v += 256) { ssc4[v] = sc4[v]; smi4[v] = mi4[v]; }
    }
    {
        const float4* in4 = reinterpret_cast<const float4*>(input + (size_t)base * IN_SZ);
        float4*       si4 = reinterpret_cast<float4*>(s_in);
        for (int v = tid; v < NB * IN_SZ / 4; v += 256) {
            int row = v / (IN_SZ / 4);
            if (base + row < N) si4[v] = in4[v];
        }
    }
    {
        int j = tid, lo = 0, hi = NNZ_C;
        while (lo < hi) { int mid = (lo + hi) >> 1; if (M[mid] < j) lo = mid + 1; else hi = mid; }
        s_seg[j] = lo;
        if (tid == 0) s_seg[OUT_SZ] = NNZ_C;
    }
    __syncthreads();

    float acc[NB];
#pragma unroll
    for (int i = 0; i < NB; ++i) acc[i] = 0.f;

    const int j = tid;
    const int k1 = s_seg[j + 1];
    for (int k = s_seg[j]; k < k1; ++k) {
        const float s = s_scale[k];
        const int   m = s_min[k];
#pragma unroll
        for (int i = 0; i < NB; ++i) acc[i] += s * s_in[i * IN_SZ + m];
    }

    float* orow = out + (size_t)base * OUT_SZ + j;
#pragma unroll
    for (int i = 0; i < NB; ++i)
        if (base + i < N) orow[(size_t)i * OUT_SZ] = acc[i];
}

// ---------------- launcher ----------------

extern "C" void kernel_launch(void* const* d_in, const int* in_sizes, int n_in,
                              void* d_out, int out_size, void* d_ws, size_t ws_size,
                              hipStream_t stream)
{
    const float* input = (const float*)d_in[0];
    const float* scale = (const float*)d_in[1];
    const int*   M_in  = (const int*)d_in[2];
    const int*   M     = (const int*)d_in[3];
    float*       out   = (float*)d_out;

    const int N = in_sizes[0] / IN_SZ;

    if (ws_size >= (size_t)(128 * 1024) && (N % BMG) == 0) {
        unsigned short* wb = (unsigned short*)d_ws;
        build_w    <<<OUT_SZ, 64, 0, stream>>>(scale, M_in, M, wb);
        gemm_direct<<<N / BMG, 256, 0, stream>>>(input, (const bf16x8*)wb, out);
    } else {
        sparse_tp_kernel<<<(N + NB - 1) / NB, 256, 0, stream>>>(input, scale, M_in, M, out, N);
    }
}

// Round 4
// 139.778 us; speedup vs baseline: 1.1296x; 1.1296x over previous
//
#include <hip/hip_runtime.h>
#include <hip/hip_bf16.h>

#define IN_SZ   256
#define OUT_SZ  256
#define NNZ_C   2048
#define NB      16      // nodes per block (fallback kernel)
#define BM      64      // GEMM rows per block
#define BK      64      // K elements per tile (f32), LDS row stride 256 B

typedef __attribute__((ext_vector_type(8))) short bf16x8;
typedef __attribute__((ext_vector_type(4))) float f32x4;

static __device__ __forceinline__ short f2bf(float f) {
    __hip_bfloat16 h = __float2bfloat16(f);
    return (short)__builtin_bit_cast(unsigned short, h);
}

// ---------------- single builder kernel (proven round 3) ----------------
// One block per output column j. Accumulate row j of W^T into LDS (f32
// atomics handle duplicate (j,m)), convert to bf16, scatter into the MFMA
// B-fragment layout consumed directly by the GEMM:
//   chunk c = (((wn*4+n)*4+kt)*2+kf)*64 + lane holds 8 consecutive k (bf16)
//   where j = wn*64+n*16+(lane&15), k = kt*64+kf*32+(lane>>4)*8+e.

__global__ void build_w(const float* __restrict__ scale,
                        const int*   __restrict__ M_in,
                        const int*   __restrict__ M,
                        unsigned short* __restrict__ wb)
{
    __shared__ float row[IN_SZ];
    const int j = blockIdx.x;
    const int t = threadIdx.x;          // 64 threads

#pragma unroll
    for (int i = t; i < IN_SZ; i += 64) row[i] = 0.f;
    __syncthreads();

#pragma unroll
    for (int k = t; k < NNZ_C; k += 64)
        if (M[k] == j) atomicAdd(&row[M_in[k]], scale[k]);
    __syncthreads();

    const int wn = j >> 6, n = (j >> 4) & 3, l15 = j & 15;
#pragma unroll
    for (int kk = t; kk < IN_SZ; kk += 64) {
        int kt = kk >> 6, kf = (kk >> 5) & 1, lhi = (kk >> 3) & 3, e = kk & 7;
        int lane = lhi * 16 + l15;
        int c = (((wn * 4 + n) * 4 + kt) * 2 + kf) * 64 + lane;
        wb[c * 8 + e] = (unsigned short)f2bf(row[kk]);
    }
}

// ---------------- staged GEMM: global_load_lds A (f32) + direct-frag B ----
// 1024 blocks x 256 thr (4 waves). Block owns 64 rows; wave w owns 64 cols.
// LDS: A tile f32, [row][slot] with 16B-slot swizzle slot_phys = slot ^ (row&7)
// applied via the GLOBAL source address (LDS dest stays linear for DMA).
// One barrier per kt; next tile's DMA + B prefetch issued before compute.

__global__ __launch_bounds__(256, 2)
void gemm_staged(const float* __restrict__ input,
                 const bf16x8* __restrict__ wfrag,
                 float* __restrict__ out)
{
    __shared__ float sA[2][BM * BK];    // 2 x 16 KB

    const int tid  = threadIdx.x;
    const int lane = tid & 63;
    const int w    = tid >> 6;          // wave id = col group
    const int l15  = lane & 15, lhi = lane >> 4;
    const long row0 = (long)blockIdx.x * BM;

    f32x4 acc[4][4];
#pragma unroll
    for (int m = 0; m < 4; ++m)
#pragma unroll
        for (int n = 0; n < 4; ++n)
            acc[m][n] = (f32x4){0.f, 0.f, 0.f, 0.f};

    bf16x8 Breg[2][8];

    // DMA one 64x64-f32 A tile into sA[buf]; 16 chunks of 1 KB (4 per wave).
    // Physical LDS byte L = c*1024 + lane*16 -> r = c*4+lhi, slot_phys = l15;
    // source holds logical slot = l15 ^ (r&7).
    auto stage = [&](int buf, int kt) {
#pragma unroll
        for (int it = 0; it < 4; ++it) {
            const int c = w * 4 + it;
            const int r = c * 4 + lhi;
            const int s = l15 ^ (r & 7);
            const float* src = input + (row0 + r) * IN_SZ + kt * BK + s * 4;
            __builtin_amdgcn_global_load_lds(
                (const __attribute__((address_space(1))) unsigned int*)src,
                (__attribute__((address_space(3))) unsigned int*)&sA[buf][c * 256],
                16, 0, 0);
        }
    };

    // prologue: tile 0 + B fragments for kt=0
    stage(0, 0);
#pragma unroll
    for (int i = 0; i < 8; ++i)
        Breg[0][i] = wfrag[(((w * 4 + (i >> 1)) * 4 + 0) * 2 + (i & 1)) * 64 + lane];
    __syncthreads();

#pragma unroll
    for (int kt = 0; kt < 4; ++kt) {
        const int cur = kt & 1;         // compile-time after unroll
        if (kt < 3) {
            // issue next-tile B prefetch + A DMA before compute (T3 minimum)
#pragma unroll
            for (int i = 0; i < 8; ++i)
                Breg[cur ^ 1][i] =
                    wfrag[(((w * 4 + (i >> 1)) * 4 + (kt + 1)) * 2 + (i & 1)) * 64 + lane];
            stage(cur ^ 1, kt + 1);
        }

#pragma unroll
        for (int kf = 0; kf < 2; ++kf) {
#pragma unroll
            for (int m = 0; m < 4; ++m) {
                const int row = m * 16 + l15;
                const int s0  = kf * 8 + lhi * 2;
                const int i0  = row * BK + ((s0 ^ (row & 7)) << 2);
                const int i1  = row * BK + (((s0 + 1) ^ (row & 7)) << 2);
                f32x4 a0 = *(const f32x4*)&sA[cur][i0];
                f32x4 a1 = *(const f32x4*)&sA[cur][i1];
                bf16x8 u;
                u[0] = f2bf(a0[0]); u[1] = f2bf(a0[1]);
                u[2] = f2bf(a0[2]); u[3] = f2bf(a0[3]);
                u[4] = f2bf(a1[0]); u[5] = f2bf(a1[1]);
                u[6] = f2bf(a1[2]); u[7] = f2bf(a1[3]);
#pragma unroll
                for (int n = 0; n < 4; ++n)
                    acc[m][n] = __builtin_amdgcn_mfma_f32_16x16x32_bf16(
                        u, Breg[cur][n * 2 + kf], acc[m][n], 0, 0, 0);
            }
        }
        __syncthreads();    // drains DMA (vmcnt) + protects buf swap
    }

    // C/D layout: col = lane&15, row = (lane>>4)*4 + r (verified rounds 1-3)
#pragma unroll
    for (int m = 0; m < 4; ++m) {
        long r0 = row0 + m * 16 + lhi * 4;
#pragma unroll
        for (int n = 0; n < 4; ++n) {
            int col = w * 64 + n * 16 + l15;
#pragma unroll
            for (int r = 0; r < 4; ++r)
                out[(r0 + r) * OUT_SZ + col] = acc[m][n][r];
        }
    }
}

// ---------------- fallback: round-1 sparse kernel ----------------

__global__ __launch_bounds__(256, 4)
void sparse_tp_kernel(const float* __restrict__ input,
                      const float* __restrict__ scale,
                      const int*   __restrict__ M_in,
                      const int*   __restrict__ M,
                      float*       __restrict__ out,
                      int N)
{
    __shared__ float s_in[NB * IN_SZ];
    __shared__ float s_scale[NNZ_C];
    __shared__ int   s_min[NNZ_C];
    __shared__ int   s_seg[OUT_SZ + 1];

    const int tid  = threadIdx.x;
    const int base = blockIdx.x * NB;

    {
        const float4* sc4  = reinterpret_cast<const float4*>(scale);
        const int4*   mi4  = reinterpret_cast<const int4*>(M_in);
        float4*       ssc4 = reinterpret_cast<float4*>(s_scale);
        int4*         smi4 = reinterpret_cast<int4*>(s_min);
        for (int v = tid; v < NNZ_C / 4; v += 256) { ssc4[v] = sc4[v]; smi4[v] = mi4[v]; }
    }
    {
        const float4* in4 = reinterpret_cast<const float4*>(input + (size_t)base * IN_SZ);
        float4*       si4 = reinterpret_cast<float4*>(s_in);
        for (int v = tid; v < NB * IN_SZ / 4; v += 256) {
            int row = v / (IN_SZ / 4);
            if (base + row < N) si4[v] = in4[v];
        }
    }
    {
        int j = tid, lo = 0, hi = NNZ_C;
        while (lo < hi) { int mid = (lo + hi) >> 1; if (M[mid] < j) lo = mid + 1; else hi = mid; }
        s_seg[j] = lo;
        if (tid == 0) s_seg[OUT_SZ] = NNZ_C;
    }
    __syncthreads();

    float acc[NB];
#pragma unroll
    for (int i = 0; i < NB; ++i) acc[i] = 0.f;

    const int j = tid;
    const int k1 = s_seg[j + 1];
    for (int k = s_seg[j]; k < k1; ++k) {
        const float s = s_scale[k];
        const int   m = s_min[k];
#pragma unroll
        for (int i = 0; i < NB; ++i) acc[i] += s * s_in[i * IN_SZ + m];
    }

    float* orow = out + (size_t)base * OUT_SZ + j;
#pragma unroll
    for (int i = 0; i < NB; ++i)
        if (base + i < N) orow[(size_t)i * OUT_SZ] = acc[i];
}

// ---------------- launcher ----------------

extern "C" void kernel_launch(void* const* d_in, const int* in_sizes, int n_in,
                              void* d_out, int out_size, void* d_ws, size_t ws_size,
                              hipStream_t stream)
{
    const float* input = (const float*)d_in[0];
    const float* scale = (const float*)d_in[1];
    const int*   M_in  = (const int*)d_in[2];
    const int*   M     = (const int*)d_in[3];
    float*       out   = (float*)d_out;

    const int N = in_sizes[0] / IN_SZ;

    if (ws_size >= (size_t)(128 * 1024) && (N % BM) == 0) {
        unsigned short* wb = (unsigned short*)d_ws;
        build_w    <<<OUT_SZ, 64, 0, stream>>>(scale, M_in, M, wb);
        gemm_staged<<<N / BM, 256, 0, stream>>>(input, (const bf16x8*)wb, out);
    } else {
        sparse_tp_kernel<<<(N + NB - 1) / NB, 256, 0, stream>>>(input, scale, M_in, M, out, N);
    }
}

// Round 5
// 131.175 us; speedup vs baseline: 1.2037x; 1.0656x over previous
//
#include <hip/hip_runtime.h>
#include <hip/hip_bf16.h>

#define IN_SZ   256
#define OUT_SZ  256
#define NNZ_C   2048
#define NB      16      // nodes per block (fallback kernel)
#define BM      64      // GEMM rows per block
#define KFULL   256     // full K staged at once (1 KB per LDS row)

typedef __attribute__((ext_vector_type(8))) short bf16x8;
typedef __attribute__((ext_vector_type(4))) float f32x4;

static __device__ __forceinline__ short f2bf(float f) {
    __hip_bfloat16 h = __float2bfloat16(f);
    return (short)__builtin_bit_cast(unsigned short, h);
}

// ---------------- builder: one block per output column j ----------------
// Segment of sorted M found by binary search (avg 8 nnz per column).
// Row j of W^T accumulated in LDS (f32 atomics handle duplicate (j,m)),
// then scattered as bf16 into the MFMA B-fragment layout:
//   chunk c = (((wn*4+n)*4+kt)*2+kf)*64 + lane holds 8 consecutive k (bf16)
//   where j = wn*64+n*16+(lane&15), k = kt*64+kf*32+(lane>>4)*8+e.

__global__ void build_w(const float* __restrict__ scale,
                        const int*   __restrict__ M_in,
                        const int*   __restrict__ M,
                        unsigned short* __restrict__ wb)
{
    __shared__ float row[IN_SZ];
    const int j = blockIdx.x;
    const int t = threadIdx.x;          // 64 threads

#pragma unroll
    for (int i = t; i < IN_SZ; i += 64) row[i] = 0.f;

    // segment bounds [lo, lo2) via binary search (uniform across threads)
    int lo = 0, hi = NNZ_C;
    while (lo < hi) { int mid = (lo + hi) >> 1; if (M[mid] < j)     lo  = mid + 1; else hi  = mid; }
    int lo2 = lo, hi2 = NNZ_C;
    while (lo2 < hi2) { int mid = (lo2 + hi2) >> 1; if (M[mid] < j + 1) lo2 = mid + 1; else hi2 = mid; }

    __syncthreads();
    for (int k = lo + t; k < lo2; k += 64)
        atomicAdd(&row[M_in[k]], scale[k]);
    __syncthreads();

    const int wn = j >> 6, n = (j >> 4) & 3, l15 = j & 15;
#pragma unroll
    for (int kk = t; kk < IN_SZ; kk += 64) {
        int kt = kk >> 6, kf = (kk >> 5) & 1, lhi = (kk >> 3) & 3, e = kk & 7;
        int lane = lhi * 16 + l15;
        int c = (((wn * 4 + n) * 4 + kt) * 2 + kf) * 64 + lane;
        wb[c * 8 + e] = (unsigned short)f2bf(row[kk]);
    }
}

// ---------------- full-K single-barrier GEMM ----------------
// 1024 blocks x 256 thr (4 waves). Block = 64 rows; wave w = 64 cols.
// Whole 64x256 f32 A panel DMA'd to LDS (64 chunks of 1 KB = one row each),
// 16-B-slot swizzle slot_phys = slot ^ (row&7) applied via the GLOBAL source
// address (LDS dest linear). One barrier; compute loop barrier-free.
// B fragments come pre-arranged from ws (L2-resident, coalesced).

__global__ __launch_bounds__(256, 2)
void gemm_fullk(const float* __restrict__ input,
                const bf16x8* __restrict__ wfrag,
                float* __restrict__ out)
{
    __shared__ float sA[BM * KFULL];    // 64 KB -> 2 blocks/CU

    const int tid  = threadIdx.x;
    const int lane = tid & 63;
    const int w    = tid >> 6;          // wave id = col group
    const int l15  = lane & 15, lhi = lane >> 4;
    const long row0 = (long)blockIdx.x * BM;

    // --- stage: 16 chunks per wave, chunk = one full LDS row (64 x 16 B) ---
#pragma unroll
    for (int it = 0; it < 16; ++it) {
        const int r = w * 16 + it;
        const float* src = input + (row0 + r) * IN_SZ + ((lane ^ (r & 7)) << 2);
        __builtin_amdgcn_global_load_lds(
            (const __attribute__((address_space(1))) unsigned int*)src,
            (__attribute__((address_space(3))) unsigned int*)&sA[r * KFULL],
            16, 0, 0);
    }

    f32x4 acc[4][4];
#pragma unroll
    for (int m = 0; m < 4; ++m)
#pragma unroll
        for (int n = 0; n < 4; ++n)
            acc[m][n] = (f32x4){0.f, 0.f, 0.f, 0.f};

    // B fragments for kt=0 (overlaps with DMA drain)
    bf16x8 Breg[2][8];
#pragma unroll
    for (int i = 0; i < 8; ++i)
        Breg[0][i] = wfrag[(((w * 4 + (i >> 1)) * 4 + 0) * 2 + (i & 1)) * 64 + lane];

    __syncthreads();    // single barrier: drains DMA (vmcnt0) once per block

#pragma unroll
    for (int kt = 0; kt < 4; ++kt) {
        const int cur = kt & 1;         // compile-time after unroll
        if (kt < 3) {
#pragma unroll
            for (int i = 0; i < 8; ++i)
                Breg[cur ^ 1][i] =
                    wfrag[(((w * 4 + (i >> 1)) * 4 + (kt + 1)) * 2 + (i & 1)) * 64 + lane];
        }
#pragma unroll
        for (int kf = 0; kf < 2; ++kf) {
#pragma unroll
            for (int m = 0; m < 4; ++m) {
                const int r  = m * 16 + l15;
                const int g0 = kt * 16 + kf * 8 + lhi * 2;     // 16-B granule idx
                f32x4 a0 = *(const f32x4*)&sA[r * KFULL + ((g0 ^ (r & 7)) << 2)];
                f32x4 a1 = *(const f32x4*)&sA[r * KFULL + (((g0 + 1) ^ (r & 7)) << 2)];
                bf16x8 u;
                u[0] = f2bf(a0[0]); u[1] = f2bf(a0[1]);
                u[2] = f2bf(a0[2]); u[3] = f2bf(a0[3]);
                u[4] = f2bf(a1[0]); u[5] = f2bf(a1[1]);
                u[6] = f2bf(a1[2]); u[7] = f2bf(a1[3]);
#pragma unroll
                for (int n = 0; n < 4; ++n)
                    acc[m][n] = __builtin_amdgcn_mfma_f32_16x16x32_bf16(
                        u, Breg[cur][n * 2 + kf], acc[m][n], 0, 0, 0);
            }
        }
    }

    // C/D layout: col = lane&15, row = (lane>>4)*4 + r (verified rounds 1-4)
#pragma unroll
    for (int m = 0; m < 4; ++m) {
        long r0 = row0 + m * 16 + lhi * 4;
#pragma unroll
        for (int n = 0; n < 4; ++n) {
            int col = w * 64 + n * 16 + l15;
#pragma unroll
            for (int r = 0; r < 4; ++r)
                out[(r0 + r) * OUT_SZ + col] = acc[m][n][r];
        }
    }
}

// ---------------- fallback: round-1 sparse kernel ----------------

__global__ __launch_bounds__(256, 4)
void sparse_tp_kernel(const float* __restrict__ input,
                      const float* __restrict__ scale,
                      const int*   __restrict__ M_in,
                      const int*   __restrict__ M,
                      float*       __restrict__ out,
                      int N)
{
    __shared__ float s_in[NB * IN_SZ];
    __shared__ float s_scale[NNZ_C];
    __shared__ int   s_min[NNZ_C];
    __shared__ int   s_seg[OUT_SZ + 1];

    const int tid  = threadIdx.x;
    const int base = blockIdx.x * NB;

    {
        const float4* sc4  = reinterpret_cast<const float4*>(scale);
        const int4*   mi4  = reinterpret_cast<const int4*>(M_in);
        float4*       ssc4 = reinterpret_cast<float4*>(s_scale);
        int4*         smi4 = reinterpret_cast<int4*>(s_min);
        for (int v = tid; v < NNZ_C / 4; v += 256) { ssc4[v] = sc4[v]; smi4[v] = mi4[v]; }
    }
    {
        const float4* in4 = reinterpret_cast<const float4*>(input + (size_t)base * IN_SZ);
        float4*       si4 = reinterpret_cast<float4*>(s_in);
        for (int v = tid; v < NB * IN_SZ / 4; v += 256) {
            int row = v / (IN_SZ / 4);
            if (base + row < N) si4[v] = in4[v];
        }
    }
    {
        int j = tid, lo = 0, hi = NNZ_C;
        while (lo < hi) { int mid = (lo + hi) >> 1; if (M[mid] < j) lo = mid + 1; else hi = mid; }
        s_seg[j] = lo;
        if (tid == 0) s_seg[OUT_SZ] = NNZ_C;
    }
    __syncthreads();

    float acc[NB];
#pragma unroll
    for (int i = 0; i < NB; ++i) acc[i] = 0.f;

    const int j = tid;
    const int k1 = s_seg[j + 1];
    for (int k = s_seg[j]; k < k1; ++k) {
        const float s = s_scale[k];
        const int   m = s_min[k];
#pragma unroll
        for (int i = 0; i < NB; ++i) acc[i] += s * s_in[i * IN_SZ + m];
    }

    float* orow = out + (size_t)base * OUT_SZ + j;
#pragma unroll
    for (int i = 0; i < NB; ++i)
        if (base + i < N) orow[(size_t)i * OUT_SZ] = acc[i];
}

// ---------------- launcher ----------------

extern "C" void kernel_launch(void* const* d_in, const int* in_sizes, int n_in,
                              void* d_out, int out_size, void* d_ws, size_t ws_size,
                              hipStream_t stream)
{
    const float* input = (const float*)d_in[0];
    const float* scale = (const float*)d_in[1];
    const int*   M_in  = (const int*)d_in[2];
    const int*   M     = (const int*)d_in[3];
    float*       out   = (float*)d_out;

    const int N = in_sizes[0] / IN_SZ;

    if (ws_size >= (size_t)(128 * 1024) && (N % BM) == 0) {
        unsigned short* wb = (unsigned short*)d_ws;
        build_w   <<<OUT_SZ, 64, 0, stream>>>(scale, M_in, M, wb);
        gemm_fullk<<<N / BM, 256, 0, stream>>>(input, (const bf16x8*)wb, out);
    } else {
        sparse_tp_kernel<<<(N + NB - 1) / NB, 256, 0, stream>>>(input, scale, M_in, M, out, N);
    }
}

// Round 6
// 130.959 us; speedup vs baseline: 1.2057x; 1.0017x over previous
//
#include <hip/hip_runtime.h>
#include <hip/hip_bf16.h>

#define IN_SZ   256
#define OUT_SZ  256
#define NNZ_C   2048
#define NB      16      // nodes per block (fallback kernel)
#define BM      128     // GEMM rows per block
#define BK      64      // K per tile (f32); LDS row = 256 B = 16 granules

typedef __attribute__((ext_vector_type(8))) short bf16x8;
typedef __attribute__((ext_vector_type(4))) float f32x4;

static __device__ __forceinline__ short f2bf(float f) {
    __hip_bfloat16 h = __float2bfloat16(f);
    return (short)__builtin_bit_cast(unsigned short, h);
}

// ---------------- builder: one block per output column j (proven r5) ------
// Binary-search segment of sorted M, accumulate row j of W^T in LDS (f32
// atomics fold duplicate (j,m)), scatter bf16 into MFMA B-fragment layout:
//   chunk c = (((wn*4+n)*4+kt)*2+kf)*64 + lane holds 8 consecutive k,
//   j = wn*64+n*16+(lane&15), k = kt*64+kf*32+(lane>>4)*8+e.

__global__ void build_w(const float* __restrict__ scale,
                        const int*   __restrict__ M_in,
                        const int*   __restrict__ M,
                        unsigned short* __restrict__ wb)
{
    __shared__ float row[IN_SZ];
    const int j = blockIdx.x;
    const int t = threadIdx.x;          // 64 threads

#pragma unroll
    for (int i = t; i < IN_SZ; i += 64) row[i] = 0.f;

    int lo = 0, hi = NNZ_C;
    while (lo < hi) { int mid = (lo + hi) >> 1; if (M[mid] < j)     lo  = mid + 1; else hi  = mid; }
    int lo2 = lo, hi2 = NNZ_C;
    while (lo2 < hi2) { int mid = (lo2 + hi2) >> 1; if (M[mid] < j + 1) lo2 = mid + 1; else hi2 = mid; }

    __syncthreads();
    for (int k = lo + t; k < lo2; k += 64)
        atomicAdd(&row[M_in[k]], scale[k]);
    __syncthreads();

    const int wn = j >> 6, n = (j >> 4) & 3, l15 = j & 15;
#pragma unroll
    for (int kk = t; kk < IN_SZ; kk += 64) {
        int kt = kk >> 6, kf = (kk >> 5) & 1, lhi = (kk >> 3) & 3, e = kk & 7;
        int lane = lhi * 16 + l15;
        int c = (((wn * 4 + n) * 4 + kt) * 2 + kf) * 64 + lane;
        wb[c * 8 + e] = (unsigned short)f2bf(row[kk]);
    }
}

// ---------------- BM=128 GEMM: DMA-staged A + direct-frag B ----------------
// 512 blocks x 512 thr (8 waves: wm in {0,1} row-halves, wn in {0..3} col
// groups; wave tile 64x64). A tile (128x64 f32, 32 KB) DMA'd by
// global_load_lds with the 16B-granule XOR swizzle g_phys = g ^ (row&7)
// applied on the GLOBAL source (LDS dest linear). Double-buffered (64 KB,
// 2 blocks/CU). One barrier per kt; next DMA + B prefetch issued first, so
// each drain has a compute-phase of delivery behind it.

__global__ __launch_bounds__(512, 4)
void gemm_bm128(const float* __restrict__ input,
                const bf16x8* __restrict__ wfrag,
                float* __restrict__ out)
{
    __shared__ float sA[2][BM * BK];    // 2 x 32 KB

    const int tid  = threadIdx.x;
    const int lane = tid & 63;
    const int wid  = tid >> 6;          // 0..7
    const int wm   = wid >> 2;          // row half
    const int wn   = wid & 3;           // col group
    const int l15  = lane & 15, lhi = lane >> 4;
    const long row0 = (long)blockIdx.x * BM;

    // one chunk = 1 KB = rows 4c..4c+3 of the tile; 32 chunks, 4 per wave
    auto stage = [&](int buf, int kt) {
#pragma unroll
        for (int it = 0; it < 4; ++it) {
            const int c = wid * 4 + it;
            const int r = c * 4 + lhi;
            const int g = l15 ^ (r & 7);
            const float* src = input + (row0 + r) * IN_SZ + kt * BK + g * 4;
            __builtin_amdgcn_global_load_lds(
                (const __attribute__((address_space(1))) unsigned int*)src,
                (__attribute__((address_space(3))) unsigned int*)&sA[buf][c * 256],
                16, 0, 0);
        }
    };

    f32x4 acc[4][4];
#pragma unroll
    for (int m = 0; m < 4; ++m)
#pragma unroll
        for (int n = 0; n < 4; ++n)
            acc[m][n] = (f32x4){0.f, 0.f, 0.f, 0.f};

    bf16x8 Breg[2][8];

    stage(0, 0);
#pragma unroll
    for (int i = 0; i < 8; ++i)
        Breg[0][i] = wfrag[(((wn * 4 + (i >> 1)) * 4 + 0) * 2 + (i & 1)) * 64 + lane];
    __syncthreads();    // drain tile-0 DMA

#pragma unroll
    for (int kt = 0; kt < 4; ++kt) {
        const int cur = kt & 1;         // compile-time after unroll
        if (kt < 3) {
            stage(cur ^ 1, kt + 1);     // issue next DMA before compute
#pragma unroll
            for (int i = 0; i < 8; ++i)
                Breg[cur ^ 1][i] =
                    wfrag[(((wn * 4 + (i >> 1)) * 4 + (kt + 1)) * 2 + (i & 1)) * 64 + lane];
        }

#pragma unroll
        for (int kf = 0; kf < 2; ++kf) {
#pragma unroll
            for (int m = 0; m < 4; ++m) {
                const int r  = wm * 64 + m * 16 + l15;
                const int g0 = kf * 8 + lhi * 2;
                f32x4 a0 = *(const f32x4*)&sA[cur][r * BK + (((g0    ) ^ (r & 7)) << 2)];
                f32x4 a1 = *(const f32x4*)&sA[cur][r * BK + (((g0 + 1) ^ (r & 7)) << 2)];
                bf16x8 u;
                u[0] = f2bf(a0[0]); u[1] = f2bf(a0[1]);
                u[2] = f2bf(a0[2]); u[3] = f2bf(a0[3]);
                u[4] = f2bf(a1[0]); u[5] = f2bf(a1[1]);
                u[6] = f2bf(a1[2]); u[7] = f2bf(a1[3]);
#pragma unroll
                for (int n = 0; n < 4; ++n)
                    acc[m][n] = __builtin_amdgcn_mfma_f32_16x16x32_bf16(
                        u, Breg[cur][n * 2 + kf], acc[m][n], 0, 0, 0);
            }
        }
        if (kt < 3) __syncthreads();    // uniform; drains next-tile DMA
    }

    // C/D layout: col = lane&15, row = (lane>>4)*4 + r (verified r1-r5)
#pragma unroll
    for (int m = 0; m < 4; ++m) {
        long r0 = row0 + wm * 64 + m * 16 + lhi * 4;
#pragma unroll
        for (int n = 0; n < 4; ++n) {
            int col = wn * 64 + n * 16 + l15;
#pragma unroll
            for (int r = 0; r < 4; ++r)
                out[(r0 + r) * OUT_SZ + col] = acc[m][n][r];
        }
    }
}

// ---------------- fallback: round-1 sparse kernel ----------------

__global__ __launch_bounds__(256, 4)
void sparse_tp_kernel(const float* __restrict__ input,
                      const float* __restrict__ scale,
                      const int*   __restrict__ M_in,
                      const int*   __restrict__ M,
                      float*       __restrict__ out,
                      int N)
{
    __shared__ float s_in[NB * IN_SZ];
    __shared__ float s_scale[NNZ_C];
    __shared__ int   s_min[NNZ_C];
    __shared__ int   s_seg[OUT_SZ + 1];

    const int tid  = threadIdx.x;
    const int base = blockIdx.x * NB;

    {
        const float4* sc4  = reinterpret_cast<const float4*>(scale);
        const int4*   mi4  = reinterpret_cast<const int4*>(M_in);
        float4*       ssc4 = reinterpret_cast<float4*>(s_scale);
        int4*         smi4 = reinterpret_cast<int4*>(s_min);
        for (int v = tid; v < NNZ_C / 4; v += 256) { ssc4[v] = sc4[v]; smi4[v] = mi4[v]; }
    }
    {
        const float4* in4 = reinterpret_cast<const float4*>(input + (size_t)base * IN_SZ);
        float4*       si4 = reinterpret_cast<float4*>(s_in);
        for (int v = tid; v < NB * IN_SZ / 4; v += 256) {
            int row = v / (IN_SZ / 4);
            if (base + row < N) si4[v] = in4[v];
        }
    }
    {
        int j = tid, lo = 0, hi = NNZ_C;
        while (lo < hi) { int mid = (lo + hi) >> 1; if (M[mid] < j) lo = mid + 1; else hi = mid; }
        s_seg[j] = lo;
        if (tid == 0) s_seg[OUT_SZ] = NNZ_C;
    }
    __syncthreads();

    float acc[NB];
#pragma unroll
    for (int i = 0; i < NB; ++i) acc[i] = 0.f;

    const int j = tid;
    const int k1 = s_seg[j + 1];
    for (int k = s_seg[j]; k < k1; ++k) {
        const float s = s_scale[k];
        const int   m = s_min[k];
#pragma unroll
        for (int i = 0; i < NB; ++i) acc[i] += s * s_in[i * IN_SZ + m];
    }

    float* orow = out + (size_t)base * OUT_SZ + j;
#pragma unroll
    for (int i = 0; i < NB; ++i)
        if (base + i < N) orow[(size_t)i * OUT_SZ] = acc[i];
}

// ---------------- launcher ----------------

extern "C" void kernel_launch(void* const* d_in, const int* in_sizes, int n_in,
                              void* d_out, int out_size, void* d_ws, size_t ws_size,
                              hipStream_t stream)
{
    const float* input = (const float*)d_in[0];
    const float* scale = (const float*)d_in[1];
    const int*   M_in  = (const int*)d_in[2];
    const int*   M     = (const int*)d_in[3];
    float*       out   = (float*)d_out;

    const int N = in_sizes[0] / IN_SZ;

    if (ws_size >= (size_t)(128 * 1024) && (N % BM) == 0) {
        unsigned short* wb = (unsigned short*)d_ws;
        build_w   <<<OUT_SZ, 64, 0, stream>>>(scale, M_in, M, wb);
        gemm_bm128<<<N / BM, 512, 0, stream>>>(input, (const bf16x8*)wb, out);
    } else {
        sparse_tp_kernel<<<(N + NB - 1) / NB, 256, 0, stream>>>(input, scale, M_in, M, out, N);
    }
}